// Round 7
// baseline (238.803 us; speedup 1.0000x reference)
//
#include <hip/hip_runtime.h>
#include <hip/hip_bf16.h>

#define DEV __device__ __forceinline__

typedef __attribute__((ext_vector_type(8))) short short8;
typedef __attribute__((ext_vector_type(4))) float f32x4;

#define MFMA16(a, b, c) __builtin_amdgcn_mfma_f32_16x16x32_bf16((a), (b), (c), 0, 0, 0)

static constexpr int B_ = 2, S_ = 2048, D_ = 1024, H_ = 16, HD_ = 64;
static constexpr long NX = (long)B_ * S_ * D_;   // 4194304
static constexpr long NW = (long)D_ * D_;        // 1048576

DEV short f2bf(float f) {
    __hip_bfloat16 h = __float2bfloat16(f);
    union { __hip_bfloat16 hh; short s; } u;
    u.hh = h;
    return u.s;
}

DEV float bf2f(short s) {
    union { float f; unsigned u; } x;
    x.u = ((unsigned)(unsigned short)s) << 16;
    return x.f;
}

// HW packed f32x2 -> bf16x2 (RTNE). No builtin on gfx950 -> inline asm.
DEV unsigned cvtpk(float a, float b) {
    unsigned r;
    asm("v_cvt_pk_bf16_f32 %0, %1, %2" : "=v"(r) : "v"(a), "v"(b));
    return r;
}

// pack 8 f32 (two float4) -> 8 bf16
DEV short8 pk8(float4 lo, float4 hi) {
    union { short8 s8; unsigned u[4]; } u;
    u.u[0] = cvtpk(lo.x, lo.y);
    u.u[1] = cvtpk(lo.z, lo.w);
    u.u[2] = cvtpk(hi.x, hi.y);
    u.u[3] = cvtpk(hi.z, hi.w);
    return u.s8;
}

DEV short8 ld8(const short* p) { return *(const short8*)p; }

// async global->LDS, 16B per lane. LDS dest = wave-uniform base + lane*16.
DEV void gld16(const short* g, short* l) {
    __builtin_amdgcn_global_load_lds(
        (const __attribute__((address_space(1))) unsigned int*)g,
        (__attribute__((address_space(3))) unsigned int*)l, 16, 0, 0);
}

// ---------------------------------------------------------------- convert (weights only)
// X (q/k/v) conversion is fused into the GEMM's A-staging now; this kernel
// only converts the 3 weight matrices (19 MB traffic, ~3 us).
__global__ __launch_bounds__(256) void convert_w(
    const float* __restrict__ wq, const float* __restrict__ wk, const float* __restrict__ wv,
    short* __restrict__ wqb, short* __restrict__ wkb, short* __restrict__ wvb) {
    long tid = (long)blockIdx.x * 256 + threadIdx.x;
    long e = tid * 4;
    const float* src; short* dst; long off;
    if      (e < NW)     { src = wq; dst = wqb; off = e; }
    else if (e < 2*NW)   { src = wk; dst = wkb; off = e - NW; }
    else                 { src = wv; dst = wvb; off = e - 2*NW; }
    float4 f = *(const float4*)(src + off);
    short4 o;
    o.x = f2bf(f.x); o.y = f2bf(f.y); o.z = f2bf(f.z); o.w = f2bf(f.w);
    *(short4*)(dst + off) = o;
}

// ---------------------------------------------------------------- GEMM
// m97 recipe + single-barrier async prefetch double-buffer + chunked
// bijective XCD swizzle (R5). NEW (R7): A-operand staged directly from the
// ORIGINAL f32 inputs — reg-staging (2x float4/lane) + v_cvt_pk_bf16_f32 +
// ds_write_b128 into the SAME bf16 LDS image the old gld16 produced.
// Eliminates the X half of convert_all (75 MB traffic + a kernel) at the
// cost of reading A as f32 (+25 MB); gemm VALUBusy was 8% -> headroom.
__global__ __launch_bounds__(256) void gemm_bias_relu(
    const float* __restrict__ X0, const float* __restrict__ X1, const float* __restrict__ X2,
    const short* __restrict__ W0, const short* __restrict__ W1, const short* __restrict__ W2,
    const float* __restrict__ b0, const float* __restrict__ b1, const float* __restrict__ b2,
    short* __restrict__ O0, short* __restrict__ O1, short* __restrict__ O2) {
    __shared__ short As[2][128 * 32];
    __shared__ short Bs[2][128 * 32];

    // chunked XCD swizzle (bijective: 768 = 8 * 96)
    const int bid = blockIdx.x;
    const int tl  = (bid & 7) * 96 + (bid >> 3);
    const int bx  = tl & 7;          // N tile (0..7)
    const int by  = (tl >> 3) & 31;  // M tile (0..31)
    const int z   = tl >> 8;         // gemm id (0..2)

    const float* X   = (z == 0) ? X0 : (z == 1) ? X1 : X2;
    const short* W   = (z == 0) ? W0 : (z == 1) ? W1 : W2;
    const float* bia = (z == 0) ? b0 : (z == 1) ? b1 : b2;
    short*       Out = (z == 0) ? O0 : (z == 1) ? O1 : O2;

    const int tid  = threadIdx.x;
    const int wid  = tid >> 6;
    const int lane = tid & 63;
    const int id   = lane & 15;
    const int quad = lane >> 4;
    const int m0 = by * 128;
    const int n0 = bx * 128;
    const int wm = (wid >> 1) * 64;
    const int wn = (wid & 1) * 64;

    // A staging source (f32): same lane->row/col mapping as the old bf16
    // gld16 (row = wid*32 + lane>>2, cols (lane&3)*8 .. +8), so the LDS
    // image is bit-identical to the old layout.
    const float* Ag = X + (long)(m0 + wid * 32 + (lane >> 2)) * D_ + (lane & 3) * 8;
    const short* Bg0 = W + (long)(n0 + wid * 32 + (lane >> 2)) * D_ + (lane & 3) * 8;
    const int offW = wid * 1024;       // wave's 32-row slab (shorts)
    const int aDst = offW + lane * 8;  // this lane's 8-short LDS slot

    f32x4 acc[4][4] = {};

    // prologue: stage buf0
    {
        float4 l0 = *(const float4*)(Ag);
        float4 h0 = *(const float4*)(Ag + 4);
        float4 l1 = *(const float4*)(Ag + 16 * D_);
        float4 h1 = *(const float4*)(Ag + 16 * D_ + 4);
        gld16(Bg0,            &Bs[0][offW]);
        gld16(Bg0 + 16 * D_,  &Bs[0][offW + 512]);
        *(short8*)(&As[0][aDst])       = pk8(l0, h0);
        *(short8*)(&As[0][aDst + 512]) = pk8(l1, h1);
    }

    for (int kk = 0; kk < D_; kk += 32) {
        const int cur = (kk >> 5) & 1;
        const int nxt = cur ^ 1;
        const bool pre = (kk + 32 < D_);
        float4 l0, h0, l1, h1;
        __syncthreads();
        if (pre) {
            l0 = *(const float4*)(Ag + kk + 32);
            h0 = *(const float4*)(Ag + kk + 36);
            l1 = *(const float4*)(Ag + 16 * D_ + kk + 32);
            h1 = *(const float4*)(Ag + 16 * D_ + kk + 36);
            gld16(Bg0 + kk + 32,            &Bs[nxt][offW]);
            gld16(Bg0 + 16 * D_ + kk + 32,  &Bs[nxt][offW + 512]);
        }

        short8 af[4], bf[4];
#pragma unroll
        for (int i = 0; i < 4; i++) af[i] = ld8(&As[cur][(wm + 16*i + id) * 32 + quad * 8]);
#pragma unroll
        for (int j = 0; j < 4; j++) bf[j] = ld8(&Bs[cur][(wn + 16*j + id) * 32 + quad * 8]);
#pragma unroll
        for (int i = 0; i < 4; i++)
#pragma unroll
            for (int j = 0; j < 4; j++)
                acc[i][j] = MFMA16(af[i], bf[j], acc[i][j]);

        if (pre) {
            // f32 loads have had the whole MFMA block to return
            *(short8*)(&As[nxt][aDst])       = pk8(l0, h0);
            *(short8*)(&As[nxt][aDst + 512]) = pk8(l1, h1);
        }
    }

#pragma unroll
    for (int j = 0; j < 4; j++) {
        int col = n0 + wn + 16*j + id;
        float bj = bia[col];
#pragma unroll
        for (int i = 0; i < 4; i++) {
#pragma unroll
            for (int r = 0; r < 4; r++) {
                int row = m0 + wm + 16*i + quad*4 + r;
                float val = fmaxf(acc[i][j][r] + bj, 0.f);
                Out[(long)row * D_ + col] = f2bf(val);
            }
        }
    }
}

// ---------------------------------------------------------------- V transpose
__global__ __launch_bounds__(256) void transpose_v(const short* __restrict__ Vp,
                                                   short* __restrict__ VT) {
    __shared__ short tile[64 * 64];
    const int bh = blockIdx.y;
    const int b = bh >> 4, h = bh & 15;
    const int s0 = blockIdx.x * 64;
    const int t = threadIdx.x;
#pragma unroll
    for (int it = 0; it < 2; it++) {
        int row = (t >> 3) + 32 * it;
        int u   = t & 7;
        short8 d = ld8(Vp + (long)(b * S_ + s0 + row) * D_ + h * HD_ + u * 8);
        *(short8*)(&tile[row * 64 + (u ^ ((row >> 3) & 7)) * 8]) = d;
    }
    __syncthreads();
#pragma unroll
    for (int it = 0; it < 2; it++) {
        int e  = (t >> 3) + 32 * it;
        int sb = (t & 7) * 8;
        short8 o;
#pragma unroll
        for (int u = 0; u < 8; u++) {
            int row = sb + u;
            o[u] = tile[row * 64 + (((e >> 3) ^ ((row >> 3) & 7)) * 8) + (e & 7)];
        }
        *(short8*)(VT + ((long)bh * HD_ + e) * S_ + s0 + sb) = o;
    }
}

// ---------------------------------------------------------------- attention
// R5-exact structure (known-good 51 us): 4 waves/block, 32 q/wave (2 groups),
// 512 blocks, async-prefetch dbuf staging via __syncthreads, XCD swizzle,
// HW cvt_pk bf16 P-pack. (R6's 16 q/wave occupancy experiment regressed
// 51->75: per-iteration amortization dominates TLP for this kernel.)
__global__ __launch_bounds__(256, 2) void attention(
    const short* __restrict__ Qb, const short* __restrict__ Kb,
    const short* __restrict__ VT, const int* __restrict__ mask,
    const float* __restrict__ queries, float* __restrict__ out) {
    __shared__ short Ks[2][64 * 64];        // [buf][key][dim], swizzled units
    __shared__ short Vs[2][64 * 64];        // [buf][dim][key], swizzled units
    __shared__ short pl[4][2 * 16 * 72];    // [wave][group][16 q][72]

    const int tid  = threadIdx.x;
    const int wid  = tid >> 6;
    const int lane = tid & 63;
    const int id   = lane & 15;
    const int quad = lane >> 4;

    // XCD swizzle: all 16 q-tiles of a (b,h) share bid%8 -> one XCD's L2.
    const int bid = blockIdx.x;          // 512
    const int w   = bid >> 3;
    const int bh  = (bid & 7) + 8 * (w & 3);
    const int qt  = w >> 2;              // 0..15
    const int b   = bh >> 4;
    const int h   = bh & 15;
    const int q0  = qt * 128 + wid * 32;

    // Q fragments (B-operand), per group, pre-scaled by 1/8 (0 if masked)
    short8 qf[2][2];
#pragma unroll
    for (int g = 0; g < 2; g++) {
        const short* qbase = Qb + (long)(b * S_ + q0 + g * 16 + id) * D_ + h * HD_ + quad * 8;
        short8 f0 = ld8(qbase);
        short8 f1 = ld8(qbase + 32);
        const float qsc = mask[b * S_ + q0 + g * 16 + id] ? 0.125f : 0.f;
#pragma unroll
        for (int i = 0; i < 8; i++) {
            f0[i] = f2bf(bf2f(f0[i]) * qsc);
            f1[i] = f2bf(bf2f(f1[i]) * qsc);
        }
        qf[g][0] = f0; qf[g][1] = f1;
    }

    // staging: row r = wid*16 + (lane>>3) (+8 for 2nd instr),
    // unit u = (lane&7) ^ (r&7)   ((r+8)&7 == r&7)
    const int srow = wid * 16 + (lane >> 3);
    const int su   = (lane & 7) ^ (srow & 7);
    const short* kg0 = Kb + ((long)b * S_ + srow) * D_ + h * HD_ + su * 8;
    const short* vg0 = VT + (((long)(b * H_ + h) * HD_) + srow) * S_ + su * 8;
    short* plw = pl[wid];

    const int swz = id & 7;  // reader-side swizzle key

    float l4[2][4] = {};
    f32x4 o[2][4] = {};

    gld16(kg0,            &Ks[0][wid * 1024]);
    gld16(kg0 + 8 * D_,   &Ks[0][wid * 1024 + 512]);
    gld16(vg0,            &Vs[0][wid * 1024]);
    gld16(vg0 + 8 * S_,   &Vs[0][wid * 1024 + 512]);

    for (int c0 = 0; c0 < S_; c0 += 64) {
        const int cur = (c0 >> 6) & 1;
        __syncthreads();  // drains stage(c0), issued one full chunk earlier
        if (c0 + 64 < S_) {
            const int nxt = cur ^ 1;
            const long cg = (long)(c0 + 64);
            gld16(kg0 + cg * D_,           &Ks[nxt][wid * 1024]);
            gld16(kg0 + cg * D_ + 8 * D_,  &Ks[nxt][wid * 1024 + 512]);
            gld16(vg0 + cg,                &Vs[nxt][wid * 1024]);
            gld16(vg0 + cg + 8 * S_,       &Vs[nxt][wid * 1024 + 512]);
        }

        // ---- S^T = K·Q^T (both query groups share A-frags)
        f32x4 s[2][4];
#pragma unroll
        for (int g = 0; g < 2; g++)
#pragma unroll
            for (int t = 0; t < 4; t++) s[g][t] = (f32x4){0.f, 0.f, 0.f, 0.f};
#pragma unroll
        for (int t = 0; t < 4; t++) {
            short8 a0 = ld8(&Ks[cur][(16*t + id) * 64 + ((quad    ) ^ swz) * 8]);
            short8 a1 = ld8(&Ks[cur][(16*t + id) * 64 + ((quad ^ 4) ^ swz) * 8]);
            s[0][t] = MFMA16(a0, qf[0][0], s[0][t]);
            s[0][t] = MFMA16(a1, qf[0][1], s[0][t]);
            s[1][t] = MFMA16(a0, qf[1][0], s[1][t]);
            s[1][t] = MFMA16(a1, qf[1][1], s[1][t]);
        }

        // ---- p = exp(s), accumulate l, HW-packed bf16 P^T to LDS
#pragma unroll
        for (int g = 0; g < 2; g++) {
            short* plg = plw + g * (16 * 72);
#pragma unroll
            for (int t = 0; t < 4; t++) {
                float p0 = __expf(s[g][t][0]);
                float p1 = __expf(s[g][t][1]);
                float p2 = __expf(s[g][t][2]);
                float p3 = __expf(s[g][t][3]);
                l4[g][0] += p0; l4[g][1] += p1; l4[g][2] += p2; l4[g][3] += p3;
                uint2 w2;
                w2.x = cvtpk(p0, p1);
                w2.y = cvtpk(p2, p3);
                *(uint2*)(&plg[id * 72 + 16 * t + quad * 4]) = w2;
            }
        }
        short8 pf[2][2];
#pragma unroll
        for (int g = 0; g < 2; g++) {
            short* plg = plw + g * (16 * 72);
            pf[g][0] = ld8(&plg[id * 72 + quad * 8]);
            pf[g][1] = ld8(&plg[id * 72 + 32 + quad * 8]);
        }

        // ---- O^T += V^T·P^T (A-frags shared by both groups)
#pragma unroll
        for (int j2 = 0; j2 < 4; j2++) {
#pragma unroll
            for (int kh = 0; kh < 2; kh++) {
                short8 va = ld8(&Vs[cur][(16*j2 + id) * 64 + (((kh << 2) + quad) ^ swz) * 8]);
                o[0][j2] = MFMA16(va, pf[0][kh], o[0][j2]);
                o[1][j2] = MFMA16(va, pf[1][kh], o[1][j2]);
            }
        }
    }

    // ---- epilogue
    const long obase = (long)b * (S_ * D_) + (long)h * (HD_ * S_);
#pragma unroll
    for (int g = 0; g < 2; g++) {
        float l = l4[g][0] + l4[g][1] + l4[g][2] + l4[g][3];
        l += __shfl_xor(l, 16);
        l += __shfl_xor(l, 32);
        const float linv = 1.f / l;
#pragma unroll
        for (int j2 = 0; j2 < 4; j2++) {
#pragma unroll
            for (int r = 0; r < 4; r++) {
                int dim = 16 * j2 + quad * 4 + r;
                long idx = obase + (long)dim * S_ + q0 + g * 16 + id;
                out[idx] = o[g][j2][r] * linv + queries[idx];
            }
        }
    }
}

// ---------------------------------------------------------------- launch
extern "C" void kernel_launch(void* const* d_in, const int* in_sizes, int n_in,
                              void* d_out, int out_size, void* d_ws, size_t ws_size,
                              hipStream_t stream) {
    const float* queries = (const float*)d_in[0];
    const float* keys    = (const float*)d_in[1];
    const float* values  = (const float*)d_in[2];
    const int*   mask    = (const int*)d_in[3];
    const float* Wq = (const float*)d_in[4];
    const float* bq = (const float*)d_in[5];
    const float* Wk = (const float*)d_in[6];
    const float* bk = (const float*)d_in[7];
    const float* Wv = (const float*)d_in[8];
    const float* bv = (const float*)d_in[9];
    float* out = (float*)d_out;

    short* ws  = (short*)d_ws;
    short* wqb = ws;
    short* wkb = wqb + NW;
    short* wvb = wkb + NW;
    short* Q   = wvb + NW;
    short* K   = Q   + NX;
    short* Vp  = K   + NX;
    short* VT  = Vp  + NX;

    convert_w<<<3072, 256, 0, stream>>>(Wq, Wk, Wv, wqb, wkb, wvb);
    gemm_bias_relu<<<768, 256, 0, stream>>>(queries, keys, values, wqb, wkb, wvb,
                                            bq, bk, bv, Q, K, Vp);
    transpose_v<<<dim3(32, 32), 256, 0, stream>>>(Vp, VT);
    attention<<<512, 256, 0, stream>>>(Q, K, VT, mask, queries, out);
}

// Round 8
// 224.745 us; speedup vs baseline: 1.0626x; 1.0626x over previous
//
#include <hip/hip_runtime.h>
#include <hip/hip_bf16.h>

#define DEV __device__ __forceinline__

typedef __attribute__((ext_vector_type(8))) short short8;
typedef __attribute__((ext_vector_type(4))) float f32x4;

#define MFMA16(a, b, c) __builtin_amdgcn_mfma_f32_16x16x32_bf16((a), (b), (c), 0, 0, 0)

static constexpr int B_ = 2, S_ = 2048, D_ = 1024, H_ = 16, HD_ = 64;
static constexpr long NX = (long)B_ * S_ * D_;   // 4194304
static constexpr long NW = (long)D_ * D_;        // 1048576

DEV short f2bf(float f) {
    __hip_bfloat16 h = __float2bfloat16(f);
    union { __hip_bfloat16 hh; short s; } u;
    u.hh = h;
    return u.s;
}

DEV float bf2f(short s) {
    union { float f; unsigned u; } x;
    x.u = ((unsigned)(unsigned short)s) << 16;
    return x.f;
}

// HW packed f32x2 -> bf16x2 (RTNE). No builtin on gfx950 -> inline asm.
DEV unsigned cvtpk(float a, float b) {
    unsigned r;
    asm("v_cvt_pk_bf16_f32 %0, %1, %2" : "=v"(r) : "v"(a), "v"(b));
    return r;
}

// pack 8 f32 (two float4) -> 8 bf16
DEV short8 pk8(float4 lo, float4 hi) {
    union { short8 s8; unsigned u[4]; } u;
    u.u[0] = cvtpk(lo.x, lo.y);
    u.u[1] = cvtpk(lo.z, lo.w);
    u.u[2] = cvtpk(hi.x, hi.y);
    u.u[3] = cvtpk(hi.z, hi.w);
    return u.s8;
}

DEV short8 ld8(const short* p) { return *(const short8*)p; }

// async global->LDS, 16B per lane. LDS dest = wave-uniform base + lane*16.
DEV void gld16(const short* g, short* l) {
    __builtin_amdgcn_global_load_lds(
        (const __attribute__((address_space(1))) unsigned int*)g,
        (__attribute__((address_space(3))) unsigned int*)l, 16, 0, 0);
}

// ---------------------------------------------------------------- convert (weights only)
__global__ __launch_bounds__(256) void convert_w(
    const float* __restrict__ wq, const float* __restrict__ wk, const float* __restrict__ wv,
    short* __restrict__ wqb, short* __restrict__ wkb, short* __restrict__ wvb) {
    long tid = (long)blockIdx.x * 256 + threadIdx.x;
    long e = tid * 4;
    const float* src; short* dst; long off;
    if      (e < NW)     { src = wq; dst = wqb; off = e; }
    else if (e < 2*NW)   { src = wk; dst = wkb; off = e - NW; }
    else                 { src = wv; dst = wvb; off = e - 2*NW; }
    float4 f = *(const float4*)(src + off);
    short4 o;
    o.x = f2bf(f.x); o.y = f2bf(f.y); o.z = f2bf(f.z); o.w = f2bf(f.w);
    *(short4*)(dst + off) = o;
}

// ---------------------------------------------------------------- GEMM
// m97 recipe + chunked XCD swizzle (R5) + fused f32->bf16 A-staging.
// R8 fix over R7: A-prefetch is pipelined ONE FULL TILE deeper — f32 loads
// for tile t+2 are issued at iter t, LDS-written at iter t+1 (after their
// latency was covered by a whole iteration incl. the barrier's vmcnt drain),
// consumed at iter t+2. R7 loaded+wrote in the same iteration -> every wave
// stalled ~600cy on vmcnt before the ds_write (gemm 45->92 us). Named AE/AO
// register sets + manual 2x unroll keep all indexing static (rule #20).
__global__ __launch_bounds__(256) void gemm_bias_relu(
    const float* __restrict__ X0, const float* __restrict__ X1, const float* __restrict__ X2,
    const short* __restrict__ W0, const short* __restrict__ W1, const short* __restrict__ W2,
    const float* __restrict__ b0, const float* __restrict__ b1, const float* __restrict__ b2,
    short* __restrict__ O0, short* __restrict__ O1, short* __restrict__ O2) {
    __shared__ short As[2][128 * 32];
    __shared__ short Bs[2][128 * 32];

    // chunked XCD swizzle (bijective: 768 = 8 * 96)
    const int bid = blockIdx.x;
    const int tl  = (bid & 7) * 96 + (bid >> 3);
    const int bx  = tl & 7;          // N tile (0..7)
    const int by  = (tl >> 3) & 31;  // M tile (0..31)
    const int z   = tl >> 8;         // gemm id (0..2)

    const float* X   = (z == 0) ? X0 : (z == 1) ? X1 : X2;
    const short* W   = (z == 0) ? W0 : (z == 1) ? W1 : W2;
    const float* bia = (z == 0) ? b0 : (z == 1) ? b1 : b2;
    short*       Out = (z == 0) ? O0 : (z == 1) ? O1 : O2;

    const int tid  = threadIdx.x;
    const int wid  = tid >> 6;
    const int lane = tid & 63;
    const int id   = lane & 15;
    const int quad = lane >> 4;
    const int m0 = by * 128;
    const int n0 = bx * 128;
    const int wm = (wid >> 1) * 64;
    const int wn = (wid & 1) * 64;

    // A staging source (f32): same lane->row/col mapping as the bf16 gld16
    // image (row = wid*32 + lane>>2, cols (lane&3)*8..+8).
    const float* Ag  = X + (long)(m0 + wid * 32 + (lane >> 2)) * D_ + (lane & 3) * 8;
    const short* Bg0 = W + (long)(n0 + wid * 32 + (lane >> 2)) * D_ + (lane & 3) * 8;
    const int offW = wid * 1024;       // wave's 32-row slab (shorts)
    const int aDst = offW + lane * 8;  // this lane's 8-short LDS slot

    f32x4 acc[4][4] = {};

#define COMPUTE(cur)                                                              \
    do {                                                                          \
        short8 af[4], bf[4];                                                      \
        _Pragma("unroll")                                                         \
        for (int i = 0; i < 4; i++)                                               \
            af[i] = ld8(&As[cur][(wm + 16*i + id) * 32 + quad * 8]);              \
        _Pragma("unroll")                                                         \
        for (int j = 0; j < 4; j++)                                               \
            bf[j] = ld8(&Bs[cur][(wn + 16*j + id) * 32 + quad * 8]);              \
        _Pragma("unroll")                                                         \
        for (int i = 0; i < 4; i++)                                               \
            _Pragma("unroll")                                                     \
            for (int j = 0; j < 4; j++)                                           \
                acc[i][j] = MFMA16(af[i], bf[j], acc[i][j]);                      \
    } while (0)

    // prologue: load tiles 0 (AE) and 1 (AO); stage B tile 0; write tile 0.
    float4 ae0 = *(const float4*)(Ag);
    float4 ae1 = *(const float4*)(Ag + 4);
    float4 ae2 = *(const float4*)(Ag + 16 * D_);
    float4 ae3 = *(const float4*)(Ag + 16 * D_ + 4);
    float4 ao0 = *(const float4*)(Ag + 32);
    float4 ao1 = *(const float4*)(Ag + 36);
    float4 ao2 = *(const float4*)(Ag + 16 * D_ + 32);
    float4 ao3 = *(const float4*)(Ag + 16 * D_ + 36);
    gld16(Bg0,            &Bs[0][offW]);
    gld16(Bg0 + 16 * D_,  &Bs[0][offW + 512]);
    *(short8*)(&As[0][aDst])       = pk8(ae0, ae1);   // one-time vmcnt stall
    *(short8*)(&As[0][aDst + 512]) = pk8(ae2, ae3);

    for (int t = 0; t < 32; t += 2) {
        const int kkO = t * 32 + 32;   // odd tile's K offset
        // ---------- even tile t (buffers [0])
        __syncthreads();               // drains B gld16(t) + in-flight A loads
        gld16(Bg0 + kkO,            &Bs[1][offW]);        // B tile t+1
        gld16(Bg0 + 16 * D_ + kkO,  &Bs[1][offW + 512]);
        COMPUTE(0);
        *(short8*)(&As[1][aDst])       = pk8(ao0, ao1);   // tile t+1 (loaded iter t-1)
        *(short8*)(&As[1][aDst + 512]) = pk8(ao2, ao3);
        if (t + 2 < 32) {                                  // issue tile t+2 loads
            ae0 = *(const float4*)(Ag + kkO + 32);
            ae1 = *(const float4*)(Ag + kkO + 36);
            ae2 = *(const float4*)(Ag + 16 * D_ + kkO + 32);
            ae3 = *(const float4*)(Ag + 16 * D_ + kkO + 36);
        }
        // ---------- odd tile t+1 (buffers [1])
        __syncthreads();
        if (t + 2 < 32) {
            gld16(Bg0 + kkO + 32,            &Bs[0][offW]);        // B tile t+2
            gld16(Bg0 + 16 * D_ + kkO + 32,  &Bs[0][offW + 512]);
        }
        COMPUTE(1);
        if (t + 2 < 32) {
            *(short8*)(&As[0][aDst])       = pk8(ae0, ae1);        // tile t+2
            *(short8*)(&As[0][aDst + 512]) = pk8(ae2, ae3);
        }
        if (t + 3 < 32) {                                          // issue tile t+3
            ao0 = *(const float4*)(Ag + kkO + 64);
            ao1 = *(const float4*)(Ag + kkO + 68);
            ao2 = *(const float4*)(Ag + 16 * D_ + kkO + 64);
            ao3 = *(const float4*)(Ag + 16 * D_ + kkO + 68);
        }
    }
#undef COMPUTE

#pragma unroll
    for (int j = 0; j < 4; j++) {
        int col = n0 + wn + 16*j + id;
        float bj = bia[col];
#pragma unroll
        for (int i = 0; i < 4; i++) {
#pragma unroll
            for (int r = 0; r < 4; r++) {
                int row = m0 + wm + 16*i + quad*4 + r;
                float val = fmaxf(acc[i][j][r] + bj, 0.f);
                Out[(long)row * D_ + col] = f2bf(val);
            }
        }
    }
}

// ---------------------------------------------------------------- V transpose
__global__ __launch_bounds__(256) void transpose_v(const short* __restrict__ Vp,
                                                   short* __restrict__ VT) {
    __shared__ short tile[64 * 64];
    const int bh = blockIdx.y;
    const int b = bh >> 4, h = bh & 15;
    const int s0 = blockIdx.x * 64;
    const int t = threadIdx.x;
#pragma unroll
    for (int it = 0; it < 2; it++) {
        int row = (t >> 3) + 32 * it;
        int u   = t & 7;
        short8 d = ld8(Vp + (long)(b * S_ + s0 + row) * D_ + h * HD_ + u * 8);
        *(short8*)(&tile[row * 64 + (u ^ ((row >> 3) & 7)) * 8]) = d;
    }
    __syncthreads();
#pragma unroll
    for (int it = 0; it < 2; it++) {
        int e  = (t >> 3) + 32 * it;
        int sb = (t & 7) * 8;
        short8 o;
#pragma unroll
        for (int u = 0; u < 8; u++) {
            int row = sb + u;
            o[u] = tile[row * 64 + (((e >> 3) ^ ((row >> 3) & 7)) * 8) + (e & 7)];
        }
        *(short8*)(VT + ((long)bh * HD_ + e) * S_ + s0 + sb) = o;
    }
}

// ---------------------------------------------------------------- attention
// R5-exact structure (known-good 51 us).
__global__ __launch_bounds__(256, 2) void attention(
    const short* __restrict__ Qb, const short* __restrict__ Kb,
    const short* __restrict__ VT, const int* __restrict__ mask,
    const float* __restrict__ queries, float* __restrict__ out) {
    __shared__ short Ks[2][64 * 64];        // [buf][key][dim], swizzled units
    __shared__ short Vs[2][64 * 64];        // [buf][dim][key], swizzled units
    __shared__ short pl[4][2 * 16 * 72];    // [wave][group][16 q][72]

    const int tid  = threadIdx.x;
    const int wid  = tid >> 6;
    const int lane = tid & 63;
    const int id   = lane & 15;
    const int quad = lane >> 4;

    // XCD swizzle: all 16 q-tiles of a (b,h) share bid%8 -> one XCD's L2.
    const int bid = blockIdx.x;          // 512
    const int w   = bid >> 3;
    const int bh  = (bid & 7) + 8 * (w & 3);
    const int qt  = w >> 2;              // 0..15
    const int b   = bh >> 4;
    const int h   = bh & 15;
    const int q0  = qt * 128 + wid * 32;

    // Q fragments (B-operand), per group, pre-scaled by 1/8 (0 if masked)
    short8 qf[2][2];
#pragma unroll
    for (int g = 0; g < 2; g++) {
        const short* qbase = Qb + (long)(b * S_ + q0 + g * 16 + id) * D_ + h * HD_ + quad * 8;
        short8 f0 = ld8(qbase);
        short8 f1 = ld8(qbase + 32);
        const float qsc = mask[b * S_ + q0 + g * 16 + id] ? 0.125f : 0.f;
#pragma unroll
        for (int i = 0; i < 8; i++) {
            f0[i] = f2bf(bf2f(f0[i]) * qsc);
            f1[i] = f2bf(bf2f(f1[i]) * qsc);
        }
        qf[g][0] = f0; qf[g][1] = f1;
    }

    // staging: row r = wid*16 + (lane>>3) (+8 for 2nd instr),
    // unit u = (lane&7) ^ (r&7)   ((r+8)&7 == r&7)
    const int srow = wid * 16 + (lane >> 3);
    const int su   = (lane & 7) ^ (srow & 7);
    const short* kg0 = Kb + ((long)b * S_ + srow) * D_ + h * HD_ + su * 8;
    const short* vg0 = VT + (((long)(b * H_ + h) * HD_) + srow) * S_ + su * 8;
    short* plw = pl[wid];

    const int swz = id & 7;  // reader-side swizzle key

    float l4[2][4] = {};
    f32x4 o[2][4] = {};

    gld16(kg0,            &Ks[0][wid * 1024]);
    gld16(kg0 + 8 * D_,   &Ks[0][wid * 1024 + 512]);
    gld16(vg0,            &Vs[0][wid * 1024]);
    gld16(vg0 + 8 * S_,   &Vs[0][wid * 1024 + 512]);

    for (int c0 = 0; c0 < S_; c0 += 64) {
        const int cur = (c0 >> 6) & 1;
        __syncthreads();  // drains stage(c0), issued one full chunk earlier
        if (c0 + 64 < S_) {
            const int nxt = cur ^ 1;
            const long cg = (long)(c0 + 64);
            gld16(kg0 + cg * D_,           &Ks[nxt][wid * 1024]);
            gld16(kg0 + cg * D_ + 8 * D_,  &Ks[nxt][wid * 1024 + 512]);
            gld16(vg0 + cg,                &Vs[nxt][wid * 1024]);
            gld16(vg0 + cg + 8 * S_,       &Vs[nxt][wid * 1024 + 512]);
        }

        // ---- S^T = K·Q^T (both query groups share A-frags)
        f32x4 s[2][4];
#pragma unroll
        for (int g = 0; g < 2; g++)
#pragma unroll
            for (int t = 0; t < 4; t++) s[g][t] = (f32x4){0.f, 0.f, 0.f, 0.f};
#pragma unroll
        for (int t = 0; t < 4; t++) {
            short8 a0 = ld8(&Ks[cur][(16*t + id) * 64 + ((quad    ) ^ swz) * 8]);
            short8 a1 = ld8(&Ks[cur][(16*t + id) * 64 + ((quad ^ 4) ^ swz) * 8]);
            s[0][t] = MFMA16(a0, qf[0][0], s[0][t]);
            s[0][t] = MFMA16(a1, qf[0][1], s[0][t]);
            s[1][t] = MFMA16(a0, qf[1][0], s[1][t]);
            s[1][t] = MFMA16(a1, qf[1][1], s[1][t]);
        }

        // ---- p = exp(s), accumulate l, HW-packed bf16 P^T to LDS
#pragma unroll
        for (int g = 0; g < 2; g++) {
            short* plg = plw + g * (16 * 72);
#pragma unroll
            for (int t = 0; t < 4; t++) {
                float p0 = __expf(s[g][t][0]);
                float p1 = __expf(s[g][t][1]);
                float p2 = __expf(s[g][t][2]);
                float p3 = __expf(s[g][t][3]);
                l4[g][0] += p0; l4[g][1] += p1; l4[g][2] += p2; l4[g][3] += p3;
                uint2 w2;
                w2.x = cvtpk(p0, p1);
                w2.y = cvtpk(p2, p3);
                *(uint2*)(&plg[id * 72 + 16 * t + quad * 4]) = w2;
            }
        }
        short8 pf[2][2];
#pragma unroll
        for (int g = 0; g < 2; g++) {
            short* plg = plw + g * (16 * 72);
            pf[g][0] = ld8(&plg[id * 72 + quad * 8]);
            pf[g][1] = ld8(&plg[id * 72 + 32 + quad * 8]);
        }

        // ---- O^T += V^T·P^T (A-frags shared by both groups)
#pragma unroll
        for (int j2 = 0; j2 < 4; j2++) {
#pragma unroll
            for (int kh = 0; kh < 2; kh++) {
                short8 va = ld8(&Vs[cur][(16*j2 + id) * 64 + (((kh << 2) + quad) ^ swz) * 8]);
                o[0][j2] = MFMA16(va, pf[0][kh], o[0][j2]);
                o[1][j2] = MFMA16(va, pf[1][kh], o[1][j2]);
            }
        }
    }

    // ---- epilogue
    const long obase = (long)b * (S_ * D_) + (long)h * (HD_ * S_);
#pragma unroll
    for (int g = 0; g < 2; g++) {
        float l = l4[g][0] + l4[g][1] + l4[g][2] + l4[g][3];
        l += __shfl_xor(l, 16);
        l += __shfl_xor(l, 32);
        const float linv = 1.f / l;
#pragma unroll
        for (int j2 = 0; j2 < 4; j2++) {
#pragma unroll
            for (int r = 0; r < 4; r++) {
                int dim = 16 * j2 + quad * 4 + r;
                long idx = obase + (long)dim * S_ + q0 + g * 16 + id;
                out[idx] = o[g][j2][r] * linv + queries[idx];
            }
        }
    }
}

// ---------------------------------------------------------------- launch
extern "C" void kernel_launch(void* const* d_in, const int* in_sizes, int n_in,
                              void* d_out, int out_size, void* d_ws, size_t ws_size,
                              hipStream_t stream) {
    const float* queries = (const float*)d_in[0];
    const float* keys    = (const float*)d_in[1];
    const float* values  = (const float*)d_in[2];
    const int*   mask    = (const int*)d_in[3];
    const float* Wq = (const float*)d_in[4];
    const float* bq = (const float*)d_in[5];
    const float* Wk = (const float*)d_in[6];
    const float* bk = (const float*)d_in[7];
    const float* Wv = (const float*)d_in[8];
    const float* bv = (const float*)d_in[9];
    float* out = (float*)d_out;

    short* ws  = (short*)d_ws;
    short* wqb = ws;
    short* wkb = wqb + NW;
    short* wvb = wkb + NW;
    short* Q   = wvb + NW;
    short* K   = Q   + NX;
    short* Vp  = K   + NX;
    short* VT  = Vp  + NX;

    convert_w<<<3072, 256, 0, stream>>>(Wq, Wk, Wv, wqb, wkb, wvb);
    gemm_bias_relu<<<768, 256, 0, stream>>>(queries, keys, values, wqb, wkb, wvb,
                                            bq, bk, bv, Q, K, Vp);
    transpose_v<<<dim3(32, 32), 256, 0, stream>>>(Vp, VT);
    attention<<<512, 256, 0, stream>>>(Q, K, VT, mask, queries, out);
}

// Round 9
// 198.278 us; speedup vs baseline: 1.2044x; 1.1335x over previous
//
#include <hip/hip_runtime.h>
#include <hip/hip_bf16.h>

#define DEV __device__ __forceinline__

typedef __attribute__((ext_vector_type(8))) short short8;
typedef __attribute__((ext_vector_type(4))) float f32x4;

#define MFMA16(a, b, c) __builtin_amdgcn_mfma_f32_16x16x32_bf16((a), (b), (c), 0, 0, 0)

static constexpr int B_ = 2, S_ = 2048, D_ = 1024, H_ = 16, HD_ = 64;
static constexpr long NX = (long)B_ * S_ * D_;   // 4194304
static constexpr long NW = (long)D_ * D_;        // 1048576

DEV short f2bf(float f) {
    __hip_bfloat16 h = __float2bfloat16(f);
    union { __hip_bfloat16 hh; short s; } u;
    u.hh = h;
    return u.s;
}

DEV float bf2f(short s) {
    union { float f; unsigned u; } x;
    x.u = ((unsigned)(unsigned short)s) << 16;
    return x.f;
}

// HW packed f32x2 -> bf16x2 (RTNE). No builtin on gfx950 -> inline asm.
DEV unsigned cvtpk(float a, float b) {
    unsigned r;
    asm("v_cvt_pk_bf16_f32 %0, %1, %2" : "=v"(r) : "v"(a), "v"(b));
    return r;
}

// pack 8 f32 (two f32x4) -> 8 bf16
DEV short8 pk8(f32x4 lo, f32x4 hi) {
    union { short8 s8; unsigned u[4]; } u;
    u.u[0] = cvtpk(lo[0], lo[1]);
    u.u[1] = cvtpk(lo[2], lo[3]);
    u.u[2] = cvtpk(hi[0], hi[1]);
    u.u[3] = cvtpk(hi[2], hi[3]);
    return u.s8;
}

DEV short8 ld8(const short* p) { return *(const short8*)p; }
DEV f32x4 ldf4(const float* p) { return *(const f32x4*)p; }

// async global->LDS, 16B per lane. LDS dest = wave-uniform base + lane*16.
DEV void gld16(const void* g, void* l) {
    __builtin_amdgcn_global_load_lds(
        (const __attribute__((address_space(1))) unsigned int*)g,
        (__attribute__((address_space(3))) unsigned int*)l, 16, 0, 0);
}

// ---------------------------------------------------------------- convert (weights only)
__global__ __launch_bounds__(256) void convert_w(
    const float* __restrict__ wq, const float* __restrict__ wk, const float* __restrict__ wv,
    short* __restrict__ wqb, short* __restrict__ wkb, short* __restrict__ wvb) {
    long tid = (long)blockIdx.x * 256 + threadIdx.x;
    long e = tid * 4;
    const float* src; short* dst; long off;
    if      (e < NW)     { src = wq; dst = wqb; off = e; }
    else if (e < 2*NW)   { src = wk; dst = wkb; off = e - NW; }
    else                 { src = wv; dst = wvb; off = e - 2*NW; }
    float4 f = *(const float4*)(src + off);
    short4 o;
    o.x = f2bf(f.x); o.y = f2bf(f.y); o.z = f2bf(f.z); o.w = f2bf(f.w);
    *(short4*)(dst + off) = o;
}

// ---------------------------------------------------------------- GEMM
// R9: convert-fusion done the R5 way. Lesson from R7/R8: __syncthreads
// drains vmcnt(0), so REG-staged A loads always eat full HBM latency at the
// barrier (92 us both rounds). Fix: stage A as raw f32 via global_load_lds
// (async, issued right after the barrier like B -> one full COMPUTE of
// flight, the proven m97/R5 pattern) and convert f32->bf16 on the READ side
// (2x ds_read_b128 + 4 cvt_pk per fragment). f32 A-tile is XOR-swizzled
// (unit ^= row&7, pre-swizzled global source, XOR'd read) to kill the
// 128B-stride same-bank conflict; 8-lane groups still cover one contiguous
// 128B row -> global coalescing preserved. LDS 48 KB -> still 3 blocks/CU.
__global__ __launch_bounds__(256) void gemm_bias_relu(
    const float* __restrict__ X0, const float* __restrict__ X1, const float* __restrict__ X2,
    const short* __restrict__ W0, const short* __restrict__ W1, const short* __restrict__ W2,
    const float* __restrict__ b0, const float* __restrict__ b1, const float* __restrict__ b2,
    short* __restrict__ O0, short* __restrict__ O1, short* __restrict__ O2) {
    __shared__ __align__(16) float As[2][128 * 32];   // f32 A tile, swizzled units
    __shared__ __align__(16) short Bs[2][128 * 32];   // bf16 B tile (proven layout)

    // chunked XCD swizzle (bijective: 768 = 8 * 96)
    const int bid = blockIdx.x;
    const int tl  = (bid & 7) * 96 + (bid >> 3);
    const int bx  = tl & 7;          // N tile (0..7)
    const int by  = (tl >> 3) & 31;  // M tile (0..31)
    const int z   = tl >> 8;         // gemm id (0..2)

    const float* X   = (z == 0) ? X0 : (z == 1) ? X1 : X2;
    const short* W   = (z == 0) ? W0 : (z == 1) ? W1 : W2;
    const float* bia = (z == 0) ? b0 : (z == 1) ? b1 : b2;
    short*       Out = (z == 0) ? O0 : (z == 1) ? O1 : O2;

    const int tid  = threadIdx.x;
    const int wid  = tid >> 6;
    const int lane = tid & 63;
    const int id   = lane & 15;
    const int quad = lane >> 4;
    const int m0 = by * 128;
    const int n0 = bx * 128;
    const int wm = (wid >> 1) * 64;
    const int wn = (wid & 1) * 64;

    // A staging (f32, 4 gld16/wave): instr p covers rows wid*32+p*8..+8.
    // lane -> row (lane>>3), unit (lane&7); global source unit pre-swizzled
    // su = (lane&7) ^ (lane>>3)  (row&7 == lane>>3 since p*8 ≡ 0 mod 8).
    const int su = (lane & 7) ^ (lane >> 3);
    const float* Agf = X + (long)(m0 + wid * 32 + (lane >> 3)) * D_ + su * 4;
    // B staging (bf16, 2 gld16/wave): proven mapping.
    const short* Bg0 = W + (long)(n0 + wid * 32 + (lane >> 2)) * D_ + (lane & 3) * 8;
    const int offWA = wid * 1024;   // wave's A slab (floats): 32 rows * 32
    const int offWB = wid * 1024;   // wave's B slab (shorts)

#define STAGE(buf, kk_)                                             \
    do {                                                            \
        gld16(Agf + (kk_),               &As[buf][offWA]);          \
        gld16(Agf + (kk_) +  8 * D_,     &As[buf][offWA + 256]);    \
        gld16(Agf + (kk_) + 16 * D_,     &As[buf][offWA + 512]);    \
        gld16(Agf + (kk_) + 24 * D_,     &As[buf][offWA + 768]);    \
        gld16(Bg0 + (kk_),               &Bs[buf][offWB]);          \
        gld16(Bg0 + (kk_) + 16 * D_,     &Bs[buf][offWB + 512]);    \
    } while (0)

    f32x4 acc[4][4] = {};

    STAGE(0, 0);

    for (int kk = 0; kk < D_; kk += 32) {
        const int cur = (kk >> 5) & 1;
        __syncthreads();                      // drains stage(kk), issued 1 iter ago
        if (kk + 32 < D_) STAGE(cur ^ 1, kk + 32);

        short8 af[4], bf[4];
#pragma unroll
        for (int i = 0; i < 4; i++) {
            const int r = wm + 16 * i + id;           // r&7 == id&7
            const int u0 = (quad * 2) ^ (id & 7);     // swizzled 16B unit
            const float* rb = &As[cur][r * 32];
            f32x4 lo = ldf4(rb + u0 * 4);
            f32x4 hi = ldf4(rb + (u0 ^ 1) * 4);
            // u0 even<->odd swap: logical lo unit is quad*2 (even). If id&7 is
            // odd, u0 is odd and holds logical unit quad*2 XOR... careful:
            // LDS unit U holds logical unit U^(r&7); reading U=quad*2^(r&7)
            // yields logical quad*2 (lo), U^1 yields quad*2+1 (hi). Correct as is.
            af[i] = pk8(lo, hi);
        }
#pragma unroll
        for (int j = 0; j < 4; j++) bf[j] = ld8(&Bs[cur][(wn + 16*j + id) * 32 + quad * 8]);
#pragma unroll
        for (int i = 0; i < 4; i++)
#pragma unroll
            for (int j = 0; j < 4; j++)
                acc[i][j] = MFMA16(af[i], bf[j], acc[i][j]);
    }
#undef STAGE

#pragma unroll
    for (int j = 0; j < 4; j++) {
        int col = n0 + wn + 16*j + id;
        float bj = bia[col];
#pragma unroll
        for (int i = 0; i < 4; i++) {
#pragma unroll
            for (int r = 0; r < 4; r++) {
                int row = m0 + wm + 16*i + quad*4 + r;
                float val = fmaxf(acc[i][j][r] + bj, 0.f);
                Out[(long)row * D_ + col] = f2bf(val);
            }
        }
    }
}

// ---------------------------------------------------------------- V transpose
__global__ __launch_bounds__(256) void transpose_v(const short* __restrict__ Vp,
                                                   short* __restrict__ VT) {
    __shared__ short tile[64 * 64];
    const int bh = blockIdx.y;
    const int b = bh >> 4, h = bh & 15;
    const int s0 = blockIdx.x * 64;
    const int t = threadIdx.x;
#pragma unroll
    for (int it = 0; it < 2; it++) {
        int row = (t >> 3) + 32 * it;
        int u   = t & 7;
        short8 d = ld8(Vp + (long)(b * S_ + s0 + row) * D_ + h * HD_ + u * 8);
        *(short8*)(&tile[row * 64 + (u ^ ((row >> 3) & 7)) * 8]) = d;
    }
    __syncthreads();
#pragma unroll
    for (int it = 0; it < 2; it++) {
        int e  = (t >> 3) + 32 * it;
        int sb = (t & 7) * 8;
        short8 o;
#pragma unroll
        for (int u = 0; u < 8; u++) {
            int row = sb + u;
            o[u] = tile[row * 64 + (((e >> 3) ^ ((row >> 3) & 7)) * 8) + (e & 7)];
        }
        *(short8*)(VT + ((long)bh * HD_ + e) * S_ + s0 + sb) = o;
    }
}

// ---------------------------------------------------------------- attention
// R5-exact structure (known-good 51 us).
__global__ __launch_bounds__(256, 2) void attention(
    const short* __restrict__ Qb, const short* __restrict__ Kb,
    const short* __restrict__ VT, const int* __restrict__ mask,
    const float* __restrict__ queries, float* __restrict__ out) {
    __shared__ short Ks[2][64 * 64];        // [buf][key][dim], swizzled units
    __shared__ short Vs[2][64 * 64];        // [buf][dim][key], swizzled units
    __shared__ short pl[4][2 * 16 * 72];    // [wave][group][16 q][72]

    const int tid  = threadIdx.x;
    const int wid  = tid >> 6;
    const int lane = tid & 63;
    const int id   = lane & 15;
    const int quad = lane >> 4;

    // XCD swizzle: all 16 q-tiles of a (b,h) share bid%8 -> one XCD's L2.
    const int bid = blockIdx.x;          // 512
    const int w   = bid >> 3;
    const int bh  = (bid & 7) + 8 * (w & 3);
    const int qt  = w >> 2;              // 0..15
    const int b   = bh >> 4;
    const int h   = bh & 15;
    const int q0  = qt * 128 + wid * 32;

    // Q fragments (B-operand), per group, pre-scaled by 1/8 (0 if masked)
    short8 qf[2][2];
#pragma unroll
    for (int g = 0; g < 2; g++) {
        const short* qbase = Qb + (long)(b * S_ + q0 + g * 16 + id) * D_ + h * HD_ + quad * 8;
        short8 f0 = ld8(qbase);
        short8 f1 = ld8(qbase + 32);
        const float qsc = mask[b * S_ + q0 + g * 16 + id] ? 0.125f : 0.f;
#pragma unroll
        for (int i = 0; i < 8; i++) {
            f0[i] = f2bf(bf2f(f0[i]) * qsc);
            f1[i] = f2bf(bf2f(f1[i]) * qsc);
        }
        qf[g][0] = f0; qf[g][1] = f1;
    }

    // staging: row r = wid*16 + (lane>>3) (+8 for 2nd instr),
    // unit u = (lane&7) ^ (r&7)   ((r+8)&7 == r&7)
    const int srow = wid * 16 + (lane >> 3);
    const int su   = (lane & 7) ^ (srow & 7);
    const short* kg0 = Kb + ((long)b * S_ + srow) * D_ + h * HD_ + su * 8;
    const short* vg0 = VT + (((long)(b * H_ + h) * HD_) + srow) * S_ + su * 8;
    short* plw = pl[wid];

    const int swz = id & 7;  // reader-side swizzle key

    float l4[2][4] = {};
    f32x4 o[2][4] = {};

    gld16(kg0,            &Ks[0][wid * 1024]);
    gld16(kg0 + 8 * D_,   &Ks[0][wid * 1024 + 512]);
    gld16(vg0,            &Vs[0][wid * 1024]);
    gld16(vg0 + 8 * S_,   &Vs[0][wid * 1024 + 512]);

    for (int c0 = 0; c0 < S_; c0 += 64) {
        const int cur = (c0 >> 6) & 1;
        __syncthreads();  // drains stage(c0), issued one full chunk earlier
        if (c0 + 64 < S_) {
            const int nxt = cur ^ 1;
            const long cg = (long)(c0 + 64);
            gld16(kg0 + cg * D_,           &Ks[nxt][wid * 1024]);
            gld16(kg0 + cg * D_ + 8 * D_,  &Ks[nxt][wid * 1024 + 512]);
            gld16(vg0 + cg,                &Vs[nxt][wid * 1024]);
            gld16(vg0 + cg + 8 * S_,       &Vs[nxt][wid * 1024 + 512]);
        }

        // ---- S^T = K·Q^T (both query groups share A-frags)
        f32x4 s[2][4];
#pragma unroll
        for (int g = 0; g < 2; g++)
#pragma unroll
            for (int t = 0; t < 4; t++) s[g][t] = (f32x4){0.f, 0.f, 0.f, 0.f};
#pragma unroll
        for (int t = 0; t < 4; t++) {
            short8 a0 = ld8(&Ks[cur][(16*t + id) * 64 + ((quad    ) ^ swz) * 8]);
            short8 a1 = ld8(&Ks[cur][(16*t + id) * 64 + ((quad ^ 4) ^ swz) * 8]);
            s[0][t] = MFMA16(a0, qf[0][0], s[0][t]);
            s[0][t] = MFMA16(a1, qf[0][1], s[0][t]);
            s[1][t] = MFMA16(a0, qf[1][0], s[1][t]);
            s[1][t] = MFMA16(a1, qf[1][1], s[1][t]);
        }

        // ---- p = exp(s), accumulate l, HW-packed bf16 P^T to LDS
#pragma unroll
        for (int g = 0; g < 2; g++) {
            short* plg = plw + g * (16 * 72);
#pragma unroll
            for (int t = 0; t < 4; t++) {
                float p0 = __expf(s[g][t][0]);
                float p1 = __expf(s[g][t][1]);
                float p2 = __expf(s[g][t][2]);
                float p3 = __expf(s[g][t][3]);
                l4[g][0] += p0; l4[g][1] += p1; l4[g][2] += p2; l4[g][3] += p3;
                uint2 w2;
                w2.x = cvtpk(p0, p1);
                w2.y = cvtpk(p2, p3);
                *(uint2*)(&plg[id * 72 + 16 * t + quad * 4]) = w2;
            }
        }
        short8 pf[2][2];
#pragma unroll
        for (int g = 0; g < 2; g++) {
            short* plg = plw + g * (16 * 72);
            pf[g][0] = ld8(&plg[id * 72 + quad * 8]);
            pf[g][1] = ld8(&plg[id * 72 + 32 + quad * 8]);
        }

        // ---- O^T += V^T·P^T (A-frags shared by both groups)
#pragma unroll
        for (int j2 = 0; j2 < 4; j2++) {
#pragma unroll
            for (int kh = 0; kh < 2; kh++) {
                short8 va = ld8(&Vs[cur][(16*j2 + id) * 64 + (((kh << 2) + quad) ^ swz) * 8]);
                o[0][j2] = MFMA16(va, pf[0][kh], o[0][j2]);
                o[1][j2] = MFMA16(va, pf[1][kh], o[1][j2]);
            }
        }
    }

    // ---- epilogue
    const long obase = (long)b * (S_ * D_) + (long)h * (HD_ * S_);
#pragma unroll
    for (int g = 0; g < 2; g++) {
        float l = l4[g][0] + l4[g][1] + l4[g][2] + l4[g][3];
        l += __shfl_xor(l, 16);
        l += __shfl_xor(l, 32);
        const float linv = 1.f / l;
#pragma unroll
        for (int j2 = 0; j2 < 4; j2++) {
#pragma unroll
            for (int r = 0; r < 4; r++) {
                int dim = 16 * j2 + quad * 4 + r;
                long idx = obase + (long)dim * S_ + q0 + g * 16 + id;
                out[idx] = o[g][j2][r] * linv + queries[idx];
            }
        }
    }
}

// ---------------------------------------------------------------- launch
extern "C" void kernel_launch(void* const* d_in, const int* in_sizes, int n_in,
                              void* d_out, int out_size, void* d_ws, size_t ws_size,
                              hipStream_t stream) {
    const float* queries = (const float*)d_in[0];
    const float* keys    = (const float*)d_in[1];
    const float* values  = (const float*)d_in[2];
    const int*   mask    = (const int*)d_in[3];
    const float* Wq = (const float*)d_in[4];
    const float* bq = (const float*)d_in[5];
    const float* Wk = (const float*)d_in[6];
    const float* bk = (const float*)d_in[7];
    const float* Wv = (const float*)d_in[8];
    const float* bv = (const float*)d_in[9];
    float* out = (float*)d_out;

    short* ws  = (short*)d_ws;
    short* wqb = ws;
    short* wkb = wqb + NW;
    short* wvb = wkb + NW;
    short* Q   = wvb + NW;
    short* K   = Q   + NX;
    short* Vp  = K   + NX;
    short* VT  = Vp  + NX;

    convert_w<<<3072, 256, 0, stream>>>(Wq, Wk, Wv, wqb, wkb, wvb);
    gemm_bias_relu<<<768, 256, 0, stream>>>(queries, keys, values, wqb, wkb, wvb,
                                            bq, bk, bv, Q, K, Vp);
    transpose_v<<<dim3(32, 32), 256, 0, stream>>>(Vp, VT);
    attention<<<512, 256, 0, stream>>>(Q, K, VT, mask, queries, out);
}